// Round 2
// baseline (110.020 us; speedup 1.0000x reference)
//
#include <hip/hip_runtime.h>
#include <hip/hip_bf16.h>

#define BT    8192      // B*T tokens (4*2048)
#define SEQ_T 2048
#define DIN   1024
#define NH    16
#define NK    8
#define DH    64
#define DO    64

typedef __bf16 bf16;
typedef __attribute__((ext_vector_type(8))) __bf16 bf16x8;
typedef __attribute__((ext_vector_type(4))) __bf16 bf16x4;
typedef __attribute__((ext_vector_type(4))) float floatx4;

// ---------------------------------------------------------------------------
// Kernel 1 (v8): scores + W transpose ONLY.  xh eliminated: moe reads x
// directly (x is L3-resident after this kernel's pass, 33.5 MB << 256 MiB).
// ---------------------------------------------------------------------------
__global__ __launch_bounds__(256) void prep_kernel(
    const float* __restrict__ x, const float* __restrict__ weight,
    const float* __restrict__ diag, const float* __restrict__ phi,
    float* __restrict__ scores_t, bf16* __restrict__ wt)
{
  int blk = blockIdx.x, tid = threadIdx.x;
  if (blk < BT / 4) {
    // ---- scores: one wave per token ----
    int wave = tid >> 6, lane = tid & 63;
    int token = blk * 4 + wave;
    const floatx4* xr = (const floatx4*)(x + (size_t)token * DIN);
    const floatx4* dg = (const floatx4*)diag;
    floatx4 acc[NK];
#pragma unroll
    for (int k = 0; k < NK; k++) acc[k] = (floatx4){0.f, 0.f, 0.f, 0.f};
#pragma unroll
    for (int it = 0; it < 4; it++) {
      floatx4 xv = xr[it * 64 + lane];
#pragma unroll
      for (int k = 0; k < NK; k++) {
        floatx4 dv = dg[k * 256 + it * 64 + lane];
        acc[k] += xv * dv;
      }
    }
    float r[NK];
#pragma unroll
    for (int k = 0; k < NK; k++)
      r[k] = (acc[k][0] + acc[k][1]) + (acc[k][2] + acc[k][3]);
#pragma unroll
    for (int k = 0; k < NK; k++) {
      float v = r[k];
#pragma unroll
      for (int off = 32; off >= 1; off >>= 1) v += __shfl_xor(v, off, 64);
      r[k] = v;
    }
    if (lane == 0) {
      int t = token & (SEQ_T - 1);
#pragma unroll
      for (int k = 0; k < NK; k++)
        scores_t[(size_t)k * BT + token] = phi[t * NK + k] + r[k];
    }
  } else {
    // ---- weight transpose: one (h,k) 64x64 tile per block, coalesced ----
    __shared__ bf16 tile[64 * 68];
    int hk = blk - BT / 4;
    const float* wsrc = weight + (size_t)hk * DH * DO;
#pragma unroll
    for (int it = 0; it < 4; it++) {
      int idx = it * 1024 + tid * 4;
      int i = idx >> 6, o = idx & 63;
      floatx4 v = *(const floatx4*)(wsrc + idx);
#pragma unroll
      for (int r = 0; r < 4; r++)
        tile[(o + r) * 68 + i] = (bf16)v[r];
    }
    __syncthreads();
#pragma unroll
    for (int it = 0; it < 4; it++) {
      int idx = it * 1024 + tid * 4;
      int o2 = idx >> 6, i2 = idx & 63;
      bf16x4 v = *(const bf16x4*)&tile[o2 * 68 + i2];
      *(bf16x4*)(wt + (size_t)hk * 4096 + idx) = v;
    }
  }
}

// ---------------------------------------------------------------------------
// Kernel 2 (v8): v6 schedule exactly (it measured best), but stages x from
// the ORIGINAL fp32 tensor (L3-hot) with on-the-fly bf16 convert — the xh
// intermediate (16.8 MB write + 33.6 MB read) is gone.
// Block = (128-token group g, head h, col-half nh), 256 threads / 4 waves.
// LDS: x 16 KB + W-half 32 KB + scores 4 KB = 52 KB -> 3 blocks/CU.
// ---------------------------------------------------------------------------
__global__ __launch_bounds__(256, 3) void moe_kernel(
    const float* __restrict__ x, const bf16* __restrict__ wt,
    const float* __restrict__ scores_t, float* __restrict__ out)
{
  __shared__ bf16  xl[128 * 64];        // 16384 B
  __shared__ bf16  wl[256 * 64];        // 32768 B  (rows R = e*32 + o)
  __shared__ float sl[NK * 128];        //  4096 B

  int bid = blockIdx.x;
  int g  = bid >> 5;            // 0..63  (128-token groups)
  int h  = (bid >> 1) & 15;
  int nh = bid & 1;             // col half (32 of the head's 64 out-cols)
  int tid = threadIdx.x, lane = tid & 63, w = tid >> 6;
  int l15 = lane & 15, q = lane >> 4;

  // ---- stage x tile from fp32 source: 1024 chunks, convert + swizzle ----
  {
    const float* xs = x + (size_t)(g * 128) * DIN + h * 64;
#pragma unroll
    for (int it = 0; it < 4; it++) {
      int idx = it * 256 + tid;           // chunk id 0..1023
      int row = idx >> 3, c = idx & 7;    // chunk = 8 bf16 = 32 B of fp32
      const float* p = xs + (size_t)row * DIN + c * 8;
      floatx4 u0 = *(const floatx4*)p;
      floatx4 u1 = *(const floatx4*)(p + 4);
      bf16x8 v;
      v[0] = (bf16)u0[0]; v[1] = (bf16)u0[1];
      v[2] = (bf16)u0[2]; v[3] = (bf16)u0[3];
      v[4] = (bf16)u1[0]; v[5] = (bf16)u1[1];
      v[6] = (bf16)u1[2]; v[7] = (bf16)u1[3];
      int pc = c ^ (row & 7);
      *(bf16x8*)(xl + row * 64 + pc * 8) = v;
    }
  }
  // ---- stage W half: 8 experts x 32 o-rows x 64 (2048 chunks), swizzled ----
  {
#pragma unroll
    for (int it = 0; it < 8; it++) {
      int idx = it * 256 + tid;               // 0..2047
      int R = idx >> 3, c = idx & 7;          // R = e*32 + o
      int e = R >> 5, o = R & 31;
      bf16x8 v = *(const bf16x8*)(wt + ((size_t)(h * NK + e) * DO + nh * 32 + o) * 64 + c * 8);
      int pc = c ^ (R & 7);
      *(bf16x8*)(wl + R * 64 + pc * 8) = v;
    }
  }
  // ---- stage scores: 8 experts x 128 tokens fp32 ----
  {
    int k = tid >> 5, t4 = (tid & 31) * 4;
    floatx4 v = *(const floatx4*)(scores_t + (size_t)k * BT + g * 128 + t4);
    *(floatx4*)(sl + k * 128 + t4) = v;
  }
  __syncthreads();

  int mh = w >> 1;              // token half (64 rows)
  int ns = w & 1;               // 16-col slice within the 32-col half

  // ---- B fragments: B[i=ki*32+q*8+j][o=ns*16+l15], all 8 experts ----
  bf16x8 b[NK][2];
#pragma unroll
  for (int e = 0; e < NK; e++) {
    int R = e * 32 + ns * 16 + l15;
#pragma unroll
    for (int ki = 0; ki < 2; ki++) {
      int pc = (ki * 4 + q) ^ (R & 7);
      b[e][ki] = *(const bf16x8*)(wl + R * 64 + pc * 8);
    }
  }

#pragma unroll
  for (int m = 0; m < 4; m++) {
    int tr = mh * 64 + m * 16;                 // token row base in block
    int row = tr + l15;
    int p0 = q ^ (row & 7), p1 = (q + 4) ^ (row & 7);
    bf16x8 a0 = *(const bf16x8*)(xl + row * 64 + p0 * 8);
    bf16x8 a1 = *(const bf16x8*)(xl + row * 64 + p1 * 8);
    floatx4 y = (floatx4){0.f, 0.f, 0.f, 0.f};
#pragma unroll
    for (int e = 0; e < NK; e++) {
      floatx4 s4 = *(const floatx4*)(sl + e * 128 + tr + q * 4);
      floatx4 z = (floatx4){0.f, 0.f, 0.f, 0.f};
      z = __builtin_amdgcn_mfma_f32_16x16x32_bf16(a0, b[e][0], z, 0, 0, 0);
      z = __builtin_amdgcn_mfma_f32_16x16x32_bf16(a1, b[e][1], z, 0, 0, 0);
      y += s4 * z;
    }
    // store: C/D layout col=l15, row=q*4+r
    int orow = g * 128 + tr + q * 4;
    float* op = out + (size_t)orow * (NH * DO) + h * DO + nh * 32 + ns * 16 + l15;
#pragma unroll
    for (int r = 0; r < 4; r++)
      op[(size_t)r * (NH * DO)] = y[r];
  }
}

extern "C" void kernel_launch(void* const* d_in, const int* in_sizes, int n_in,
                              void* d_out, int out_size, void* d_ws, size_t ws_size,
                              hipStream_t stream) {
  const float* x      = (const float*)d_in[0];
  const float* weight = (const float*)d_in[1];
  const float* diag   = (const float*)d_in[2];
  const float* phi    = (const float*)d_in[3];
  float* out = (float*)d_out;

  // workspace: [0,1MiB) wt dense | [2MiB) scores_t 256KiB
  bf16*  wt       = (bf16*)d_ws;
  float* scores_t = (float*)((char*)d_ws + (2u << 20));

  prep_kernel<<<BT / 4 + NH * NK, 256, 0, stream>>>(x, weight, diag, phi,
                                                    scores_t, wt);
  // 64 token-groups x 16 heads x 2 col-halves
  moe_kernel<<<64 * NH * 2, 256, 0, stream>>>(x, wt, scores_t, out);
}